// Round 1
// baseline (615.485 us; speedup 1.0000x reference)
//
#include <hip/hip_runtime.h>
#include <hip/hip_bf16.h>
#include <math.h>

#define Fdim 40
#define Edim 64
#define K2   128   // 2*E
#define Tdim 2
#define EPSV 1e-5f

// ---------------------------------------------------------------------------
// Kernel A: build per-tower adjacency (T x F x F) into workspace.
// adj_raw = relu(prod_m masker[t,m,:,:]); mask = adj_raw != 0
// LayerNorm over dim -2 (stats per column f over g, gamma/beta indexed by g)
// logits = ln(adj) + (1-mask)*(-1e9) + eye; softmax over g; * mask
// ---------------------------------------------------------------------------
__global__ void adj_kernel(const float* __restrict__ masker,
                           const float* __restrict__ ln_gamma,
                           const float* __restrict__ ln_beta,
                           float* __restrict__ adjws) {
    const int t = blockIdx.x;
    const int tid = threadIdx.x;
    __shared__ float araw[Fdim][Fdim];

    for (int i = tid; i < Fdim * Fdim; i += 64) {
        int g = i / Fdim, ff = i % Fdim;
        const float* mb = masker + t * (3 * Fdim * Fdim) + g * Fdim + ff;
        float p = mb[0] * mb[Fdim * Fdim] * mb[2 * Fdim * Fdim];
        araw[g][ff] = p > 0.f ? p : 0.f;
    }
    __syncthreads();

    const int f = tid;
    if (f < Fdim) {
        // column stats over g
        float mu = 0.f, m2 = 0.f;
        #pragma unroll
        for (int g = 0; g < Fdim; ++g) {
            float v = araw[g][f];
            mu += v; m2 += v * v;
        }
        mu *= (1.f / Fdim); m2 *= (1.f / Fdim);
        float inv = rsqrtf(m2 - mu * mu + EPSV);

        float logits[Fdim];
        float mx = -1e30f;
        #pragma unroll
        for (int g = 0; g < Fdim; ++g) {
            float v = araw[g][f];
            float l = (v - mu) * inv * ln_gamma[g] + ln_beta[g];
            if (v == 0.f) l += -1e9f;
            if (g == f) l += 1.f;
            logits[g] = l;
            mx = fmaxf(mx, l);
        }
        float den = 0.f;
        #pragma unroll
        for (int g = 0; g < Fdim; ++g) {
            float p = expf(logits[g] - mx);
            logits[g] = p;
            den += p;
        }
        float rden = 1.f / den;
        #pragma unroll
        for (int g = 0; g < Fdim; ++g) {
            float msk = (araw[g][f] != 0.f) ? 1.f : 0.f;
            adjws[(t * Fdim + g) * Fdim + f] = logits[g] * rden * msk;
        }
    }
}

// ---------------------------------------------------------------------------
// Kernel B: one block per (b, t). 256 threads = 4 waves.
// thread: e = tid & 63 (lane), fq = tid >> 6 (wave); owns f = fq*10 + i, i<10.
// ---------------------------------------------------------------------------
__global__ __launch_bounds__(256) void main_kernel(
    const float* __restrict__ x,        // (B, F, E)
    const float* __restrict__ adjws,    // (T, F, F)
    const float* __restrict__ w_t,      // (1, T, 1, 2E, E)
    const float* __restrict__ b_t,      // (T, 1, F, E)
    const float* __restrict__ bn_gamma,
    const float* __restrict__ bn_beta,
    const float* __restrict__ bn_mean,
    const float* __restrict__ bn_var,
    const float* __restrict__ gate_w,   // (F*E, F)
    const float* __restrict__ gate_b,   // (F,)
    float* __restrict__ out)            // (B, T, E)
{
    const int bid = blockIdx.x;
    const int b = bid >> 1, t = bid & 1;
    const int tid = threadIdx.x;
    const int e = tid & 63, fq = tid >> 6;

    __shared__ float xs[Fdim][Edim];     // 10 KB
    __shared__ float adjs[Fdim][Fdim];   // 6.4 KB
    __shared__ float xc[Fdim][K2];       // 20 KB
    __shared__ float xcs[Fdim][Edim];    // 10 KB
    __shared__ float gpart[4][Fdim];
    __shared__ float gvals[Fdim];

    // stage x[b] and adj[t]
    const float* xb = x + (size_t)b * Fdim * Edim;
    for (int i = tid; i < Fdim * Edim; i += 256) xs[i >> 6][i & 63] = xb[i];
    const float* ab = adjws + t * Fdim * Fdim;
    for (int i = tid; i < Fdim * Fdim; i += 256) adjs[i / Fdim][i % Fdim] = ab[i];
    __syncthreads();

    // nei[f][e] = sum_g xs[g][e] * adj[g][f], for this thread's 10 f rows
    float acc[10];
    #pragma unroll
    for (int i = 0; i < 10; ++i) acc[i] = 0.f;
    for (int g = 0; g < Fdim; ++g) {
        float xv = xs[g][e];
        #pragma unroll
        for (int i = 0; i < 10; ++i) acc[i] += xv * adjs[g][fq * 10 + i];
    }

    // BatchNorm (inference affine) + concat -> xc[f][0:128]
    const int bnbase = t * Fdim * K2;
    #pragma unroll
    for (int i = 0; i < 10; ++i) {
        int f = fq * 10 + i;
        int i1 = bnbase + f * K2 + e;
        int i2 = i1 + Edim;
        float s1 = bn_gamma[i1] * rsqrtf(bn_var[i1] + EPSV);
        float o1 = bn_beta[i1] - bn_mean[i1] * s1;
        float s2 = bn_gamma[i2] * rsqrtf(bn_var[i2] + EPSV);
        float o2 = bn_beta[i2] - bn_mean[i2] * s2;
        xc[f][e] = xs[f][e] * s1 + o1;
        xc[f][Edim + e] = acc[i] * s2 + o2;
    }
    __syncthreads();

    // xcur[f][e] = b_t[t,0,f,e] + sum_k xc[f][k] * W[k][e]
    const float* W  = w_t + t * K2 * Edim;
    const float* bt = b_t + t * Fdim * Edim;
    float acc2[10];
    #pragma unroll
    for (int i = 0; i < 10; ++i) acc2[i] = bt[(fq * 10 + i) * Edim + e];
    for (int k = 0; k < K2; ++k) {
        float wv = W[k * Edim + e];
        #pragma unroll
        for (int i = 0; i < 10; ++i) acc2[i] += xc[fq * 10 + i][k] * wv;
    }
    #pragma unroll
    for (int i = 0; i < 10; ++i) xcs[fq * 10 + i][e] = acc2[i];

    // gating partials: part[f] = sum over this thread's (f', e) of
    //                  xcur[f'][e] * gate_w[(f'*64+e)*40 + f]
    float part[Fdim];
    #pragma unroll
    for (int f = 0; f < Fdim; ++f) part[f] = 0.f;
    #pragma unroll
    for (int i = 0; i < 10; ++i) {
        int row = (fq * 10 + i) * Edim + e;
        float xv = acc2[i];
        const float4* gw4 = reinterpret_cast<const float4*>(gate_w + (size_t)row * Fdim);
        #pragma unroll
        for (int j = 0; j < 10; ++j) {
            float4 gv = gw4[j];
            part[j * 4 + 0] += xv * gv.x;
            part[j * 4 + 1] += xv * gv.y;
            part[j * 4 + 2] += xv * gv.z;
            part[j * 4 + 3] += xv * gv.w;
        }
    }
    // full-wave (64-lane) butterfly reduction of all 40 partials
    #pragma unroll
    for (int f = 0; f < Fdim; ++f) {
        float v = part[f];
        v += __shfl_xor(v, 1);
        v += __shfl_xor(v, 2);
        v += __shfl_xor(v, 4);
        v += __shfl_xor(v, 8);
        v += __shfl_xor(v, 16);
        v += __shfl_xor(v, 32);
        part[f] = v;
    }
    if (e == 0) {
        #pragma unroll
        for (int f = 0; f < Fdim; ++f) gpart[fq][f] = part[f];
    }
    __syncthreads();

    if (tid < Fdim) {
        gvals[tid] = gate_b[tid] + gpart[0][tid] + gpart[1][tid]
                   + gpart[2][tid] + gpart[3][tid];
    }
    __syncthreads();

    // softmax over f + weighted sum -> out[b, t, e]
    if (tid < Edim) {
        float mx = -1e30f;
        #pragma unroll
        for (int f = 0; f < Fdim; ++f) mx = fmaxf(mx, gvals[f]);
        float den = 0.f, o = 0.f;
        #pragma unroll
        for (int f = 0; f < Fdim; ++f) {
            float p = expf(gvals[f] - mx);
            den += p;
            o += xcs[f][tid] * p;
        }
        out[(size_t)bid * Edim + tid] = o / den;
    }
}

extern "C" void kernel_launch(void* const* d_in, const int* in_sizes, int n_in,
                              void* d_out, int out_size, void* d_ws, size_t ws_size,
                              hipStream_t stream) {
    (void)in_sizes; (void)n_in; (void)out_size; (void)ws_size;
    const float* x        = (const float*)d_in[0];
    const float* masker   = (const float*)d_in[1];
    const float* ln_gamma = (const float*)d_in[2];
    const float* ln_beta  = (const float*)d_in[3];
    const float* w_t      = (const float*)d_in[4];
    const float* b_t      = (const float*)d_in[5];
    const float* bn_gamma = (const float*)d_in[6];
    const float* bn_beta  = (const float*)d_in[7];
    const float* bn_mean  = (const float*)d_in[8];
    const float* bn_var   = (const float*)d_in[9];
    const float* gate_w   = (const float*)d_in[10];
    const float* gate_b   = (const float*)d_in[11];
    float* out = (float*)d_out;
    float* adjws = (float*)d_ws;  // T*F*F floats = 12.8 KB

    adj_kernel<<<Tdim, 64, 0, stream>>>(masker, ln_gamma, ln_beta, adjws);

    const int B = 4096;
    main_kernel<<<B * Tdim, 256, 0, stream>>>(
        x, adjws, w_t, b_t, bn_gamma, bn_beta, bn_mean, bn_var,
        gate_w, gate_b, out);
}

// Round 2
// 109.791 us; speedup vs baseline: 5.6060x; 5.6060x over previous
//
#include <hip/hip_runtime.h>
#include <hip/hip_bf16.h>
#include <math.h>

#define Fdim 40
#define Edim 64
#define K2   128
#define Tdim 2
#define EPSV 1e-5f

typedef __attribute__((ext_vector_type(8))) short short8;
typedef __attribute__((ext_vector_type(4))) short short4v;
typedef __attribute__((ext_vector_type(4))) float f32x4;

__device__ __forceinline__ short f2b(float f) {
    unsigned u = __builtin_bit_cast(unsigned, f);
    unsigned r = (u + 0x7fffu + ((u >> 16) & 1u)) >> 16;
    return (short)r;
}
__device__ __forceinline__ float b2f(short h) {
    unsigned u = ((unsigned)(unsigned short)h) << 16;
    return __builtin_bit_cast(float, u);
}
__device__ __forceinline__ f32x4 mfma16(short8 a, short8 b, f32x4 c) {
    return __builtin_amdgcn_mfma_f32_16x16x32_bf16(a, b, c, 0, 0, 0);
}

// ws layout (shorts/floats):
//   adjT bf16 [2][48][64]   : shorts 0      .. 6144
//   WT   bf16 [2][64][128]  : shorts 6144   .. 22528
//   gwT  bf16 [48][2560]    : shorts 22528  .. 145408
//   bnS  f32  [2][40][128]  : floats at byte 290816
//   bnO  f32  [2][40][128]  : floats at byte 331776   (total 372736 B)

// ---------------------------------------------------------------------------
// adjacency: relu(prod masker) -> LN(dim -2) -> mask/eye -> softmax(g) -> *mask
// output: A-operand adjT[t][f][g] = adj[g][f], bf16, zero-padded to 48x64
// ---------------------------------------------------------------------------
__global__ void adj_kernel(const float* __restrict__ masker,
                           const float* __restrict__ ln_gamma,
                           const float* __restrict__ ln_beta,
                           short* __restrict__ adjT) {
    const int t = blockIdx.x;
    const int tid = threadIdx.x;
    __shared__ float araw[Fdim][Fdim];

    for (int i = tid; i < Fdim * Fdim; i += 64) {
        int g = i / Fdim, ff = i % Fdim;
        const float* mb = masker + t * (3 * Fdim * Fdim) + g * Fdim + ff;
        float p = mb[0] * mb[Fdim * Fdim] * mb[2 * Fdim * Fdim];
        araw[g][ff] = p > 0.f ? p : 0.f;
    }
    __syncthreads();

    const int f = tid;
    if (f < 40) {
        float mu = 0.f, m2 = 0.f;
        #pragma unroll
        for (int g = 0; g < Fdim; ++g) {
            float v = araw[g][f];
            mu += v; m2 += v * v;
        }
        mu *= (1.f / Fdim); m2 *= (1.f / Fdim);
        float inv = rsqrtf(m2 - mu * mu + EPSV);

        float logits[Fdim];
        float mx = -1e30f;
        #pragma unroll
        for (int g = 0; g < Fdim; ++g) {
            float v = araw[g][f];
            float l = (v - mu) * inv * ln_gamma[g] + ln_beta[g];
            if (v == 0.f) l += -1e9f;
            if (g == f) l += 1.f;
            logits[g] = l;
            mx = fmaxf(mx, l);
        }
        float den = 0.f;
        #pragma unroll
        for (int g = 0; g < Fdim; ++g) {
            float p = expf(logits[g] - mx);
            logits[g] = p;
            den += p;
        }
        float rden = 1.f / den;
        short* row = adjT + t * 3072 + f * 64;   // adjT[t][f][g]
        #pragma unroll
        for (int g = 0; g < Fdim; ++g) {
            float msk = (araw[g][f] != 0.f) ? 1.f : 0.f;
            row[g] = f2b(logits[g] * rden * msk);
        }
        for (int g = Fdim; g < 64; ++g) row[g] = 0;
    } else if (f < 48) {
        short* row = adjT + t * 3072 + f * 64;
        for (int g = 0; g < 64; ++g) row[g] = 0;
    }
}

// ---------------------------------------------------------------------------
// prep: WT[t][e][k] bf16, gwT[fo][k] bf16 (rows 40..47 zero), bnS/bnO f32
// ---------------------------------------------------------------------------
__global__ void prep_kernel(const float* __restrict__ w_t,
                            const float* __restrict__ gate_w,
                            const float* __restrict__ bn_gamma,
                            const float* __restrict__ bn_beta,
                            const float* __restrict__ bn_mean,
                            const float* __restrict__ bn_var,
                            short* __restrict__ WT,
                            short* __restrict__ gwT,
                            float* __restrict__ bnS,
                            float* __restrict__ bnO) {
    int i = blockIdx.x * 256 + threadIdx.x;
    if (i < 16384) {
        int t = i >> 13, r = i & 8191, e = r >> 7, k = r & 127;
        WT[i] = f2b(w_t[t * 8192 + k * 64 + e]);
    } else if (i < 139264) {
        int j = i - 16384;
        int fo = j / 2560, k = j - fo * 2560;
        gwT[j] = (fo < 40) ? f2b(gate_w[k * 40 + fo]) : (short)0;
    } else if (i < 149504) {
        int j = i - 139264;
        float s = bn_gamma[j] * rsqrtf(bn_var[j] + EPSV);
        bnS[j] = s;
        bnO[j] = bn_beta[j] - bn_mean[j] * s;
    }
}

// ---------------------------------------------------------------------------
// main: 1 block = 16 samples x 1 tower. 4 waves, wave w owns samples 4w..4w+3.
// LDS: nei[4][48][72] bf16 | xcur[16][40][72] bf16 | gred[4][3][64] f32x4 |
//      g_lds[16][40] f32   -> 134656 B dynamic
// ---------------------------------------------------------------------------
__global__ __launch_bounds__(256) void main_kernel(
    const float* __restrict__ x,
    const short* __restrict__ adjT,
    const short* __restrict__ WT,
    const short* __restrict__ gwT,
    const float* __restrict__ bnS,
    const float* __restrict__ bnO,
    const float* __restrict__ b_t,
    const float* __restrict__ gate_b,
    float* __restrict__ out)
{
    extern __shared__ char smem[];
    short* nei_all = (short*)smem;                       // 4*48*72 shorts
    short* xcur    = nei_all + 4 * 48 * 72;              // 16*40*72 shorts
    f32x4* gred    = (f32x4*)(xcur + 16 * 40 * 72);      // 4*3*64 f32x4
    float* g_lds   = (float*)(gred + 4 * 3 * 64);        // 16*40 f32

    const int tid = threadIdx.x;
    const int w = tid >> 6, lane = tid & 63;
    const int er = lane & 15, q = lane >> 4;
    const int t = blockIdx.x & 1;
    const int bbase = (blockIdx.x >> 1) * 16;

    short* nei_w = nei_all + w * (48 * 72);
    const short* adjTt = adjT + t * 3072;
    const short* WTt   = WT + t * 8192;
    const float* bnSt  = bnS + t * 5120;
    const float* bnOt  = bnO + t * 5120;
    const float* btt   = b_t + t * 2560;

    for (int i = 0; i < 4; ++i) {
        const int ls = w * 4 + i;
        const float* xb = x + (size_t)(bbase + ls) * 2560;

        // ---------------- phase N: nei = adjT * x  (per-sample 40x64)
        short8 Bf[2][4];
        #pragma unroll
        for (int kt = 0; kt < 2; ++kt)
            #pragma unroll
            for (int nt = 0; nt < 4; ++nt) {
                int e = nt * 16 + er;
                short8 v;
                #pragma unroll
                for (int j = 0; j < 8; ++j) {
                    int g = kt * 32 + q * 8 + j;
                    float xv = (g < 40) ? xb[g * 64 + e] : 0.f;
                    v[j] = f2b(xv);
                }
                Bf[kt][nt] = v;
            }
        #pragma unroll
        for (int mt = 0; mt < 3; ++mt) {
            const short* arow = adjTt + (mt * 16 + er) * 64 + q * 8;
            short8 A0 = *(const short8*)(arow);
            short8 A1 = *(const short8*)(arow + 32);
            f32x4 acc[4];
            #pragma unroll
            for (int nt = 0; nt < 4; ++nt) {
                f32x4 z = {0.f, 0.f, 0.f, 0.f};
                z = mfma16(A0, Bf[0][nt], z);
                acc[nt] = mfma16(A1, Bf[1][nt], z);
            }
            // BN2 fused into nei write (cols 64..127 of xc)
            #pragma unroll
            for (int nt = 0; nt < 4; ++nt) {
                #pragma unroll
                for (int r = 0; r < 4; ++r) {
                    int f = mt * 16 + q * 4 + r;
                    if (f < 40) {
                        int e = nt * 16 + er;
                        int ci = f * 128 + 64 + e;
                        float vv = acc[nt][r] * bnSt[ci] + bnOt[ci];
                        nei_w[f * 72 + e] = f2b(vv);
                    }
                }
            }
        }
        __syncthreads();

        // ---------------- phase M: xcur = BN(concat(x,nei)) @ W + b
        short* xrow = xcur + ls * 2880;
        #pragma unroll
        for (int mt = 0; mt < 3; ++mt) {
            f32x4 acc[4];
            #pragma unroll
            for (int nt = 0; nt < 4; ++nt) { f32x4 z = {0.f,0.f,0.f,0.f}; acc[nt] = z; }
            #pragma unroll
            for (int kt = 0; kt < 4; ++kt) {
                short8 A;
                if (kt < 2) {
                    int f = mt * 16 + er;
                    if (f < 40) {
                        int kb = kt * 32 + q * 8;
                        const float4* xp = (const float4*)(xb + f * 64 + kb);
                        float4 x0 = xp[0], x1 = xp[1];
                        const float4* sp = (const float4*)(bnSt + f * 128 + kb);
                        const float4* op = (const float4*)(bnOt + f * 128 + kb);
                        float4 s0 = sp[0], s1 = sp[1], o0 = op[0], o1 = op[1];
                        A[0] = f2b(x0.x * s0.x + o0.x);
                        A[1] = f2b(x0.y * s0.y + o0.y);
                        A[2] = f2b(x0.z * s0.z + o0.z);
                        A[3] = f2b(x0.w * s0.w + o0.w);
                        A[4] = f2b(x1.x * s1.x + o1.x);
                        A[5] = f2b(x1.y * s1.y + o1.y);
                        A[6] = f2b(x1.z * s1.z + o1.z);
                        A[7] = f2b(x1.w * s1.w + o1.w);
                    } else {
                        short8 za = {0,0,0,0,0,0,0,0};
                        A = za;
                    }
                } else {
                    A = *(const short8*)(nei_w + (mt * 16 + er) * 72 + (kt - 2) * 32 + q * 8);
                }
                #pragma unroll
                for (int nt = 0; nt < 4; ++nt) {
                    short8 B = *(const short8*)(WTt + (nt * 16 + er) * 128 + kt * 32 + q * 8);
                    acc[nt] = mfma16(A, B, acc[nt]);
                }
            }
            #pragma unroll
            for (int nt = 0; nt < 4; ++nt) {
                #pragma unroll
                for (int r = 0; r < 4; ++r) {
                    int f = mt * 16 + q * 4 + r;
                    if (f < 40) {
                        int e = nt * 16 + er;
                        float vv = acc[nt][r] + btt[f * 64 + e];
                        xrow[f * 72 + e] = f2b(vv);
                    }
                }
            }
        }
        __syncthreads();
    }

    // ---------------- phase G: gate logits, M=16 samples, K=2560, N=40(48)
    {
        f32x4 g0 = {0.f,0.f,0.f,0.f}, g1 = g0, g2 = g0;
        for (int kk = 0; kk < 20; ++kk) {
            int kt = w * 20 + kk;
            int k = kt * 32 + q * 8;
            int f = k >> 6, kin = k & 63;
            short8 A = *(const short8*)(xcur + er * 2880 + f * 72 + kin);
            g0 = mfma16(A, *(const short8*)(gwT + (er)      * 2560 + k), g0);
            g1 = mfma16(A, *(const short8*)(gwT + (16 + er) * 2560 + k), g1);
            g2 = mfma16(A, *(const short8*)(gwT + (32 + er) * 2560 + k), g2);
        }
        gred[(w * 3 + 0) * 64 + lane] = g0;
        gred[(w * 3 + 1) * 64 + lane] = g1;
        gred[(w * 3 + 2) * 64 + lane] = g2;
    }
    __syncthreads();
    if (w == 0) {
        #pragma unroll
        for (int nt = 0; nt < 3; ++nt) {
            f32x4 v = gred[nt * 64 + lane] + gred[(3 + nt) * 64 + lane]
                    + gred[(6 + nt) * 64 + lane] + gred[(9 + nt) * 64 + lane];
            int fo = nt * 16 + er;
            if (fo < 40) {
                float gb = gate_b[fo];
                #pragma unroll
                for (int r = 0; r < 4; ++r)
                    g_lds[(q * 4 + r) * 40 + fo] = v[r] + gb;
            }
        }
    }
    __syncthreads();

    // ---------------- final: softmax over f + weighted sum
    {
        int s = tid >> 4, e0 = (tid & 15) * 4;
        const float* gr = g_lds + s * 40;
        float m = gr[0];
        #pragma unroll
        for (int f2 = 1; f2 < 40; ++f2) m = fmaxf(m, gr[f2]);
        float wgt[40];
        float den = 0.f;
        #pragma unroll
        for (int f2 = 0; f2 < 40; ++f2) {
            float p = expf(gr[f2] - m);
            wgt[f2] = p;
            den += p;
        }
        float o0 = 0.f, o1 = 0.f, o2 = 0.f, o3 = 0.f;
        const short* xr = xcur + s * 2880;
        #pragma unroll
        for (int f2 = 0; f2 < 40; ++f2) {
            short4v xv = *(const short4v*)(xr + f2 * 72 + e0);
            float wf = wgt[f2];
            o0 += wf * b2f(xv[0]);
            o1 += wf * b2f(xv[1]);
            o2 += wf * b2f(xv[2]);
            o3 += wf * b2f(xv[3]);
        }
        float rd = 1.f / den;
        float4 ov = { o0 * rd, o1 * rd, o2 * rd, o3 * rd };
        *(float4*)(out + ((size_t)(bbase + s) * 2 + t) * 64 + e0) = ov;
    }
}

extern "C" void kernel_launch(void* const* d_in, const int* in_sizes, int n_in,
                              void* d_out, int out_size, void* d_ws, size_t ws_size,
                              hipStream_t stream) {
    (void)in_sizes; (void)n_in; (void)out_size; (void)ws_size;
    const float* x        = (const float*)d_in[0];
    const float* masker   = (const float*)d_in[1];
    const float* ln_gamma = (const float*)d_in[2];
    const float* ln_beta  = (const float*)d_in[3];
    const float* w_t      = (const float*)d_in[4];
    const float* b_t      = (const float*)d_in[5];
    const float* bn_gamma = (const float*)d_in[6];
    const float* bn_beta  = (const float*)d_in[7];
    const float* bn_mean  = (const float*)d_in[8];
    const float* bn_var   = (const float*)d_in[9];
    const float* gate_w   = (const float*)d_in[10];
    const float* gate_b   = (const float*)d_in[11];
    float* out = (float*)d_out;

    short* adjT = (short*)d_ws;
    short* WT   = adjT + 6144;
    short* gwT  = WT + 16384;
    float* bnS  = (float*)(gwT + 122880);
    float* bnO  = bnS + 10240;

    adj_kernel<<<Tdim, 64, 0, stream>>>(masker, ln_gamma, ln_beta, adjT);
    prep_kernel<<<584, 256, 0, stream>>>(w_t, gate_w, bn_gamma, bn_beta, bn_mean,
                                         bn_var, WT, gwT, bnS, bnO);

    constexpr int SMEM_BYTES = 4*48*72*2 + 16*40*72*2 + 4*3*64*16 + 16*40*4; // 134656
    (void)hipFuncSetAttribute((const void*)main_kernel,
                              hipFuncAttributeMaxDynamicSharedMemorySize, SMEM_BYTES);
    main_kernel<<<512, 256, SMEM_BYTES, stream>>>(
        x, adjT, WT, gwT, bnS, bnO, b_t, gate_b, out);
}